// Round 9
// baseline (125.319 us; speedup 1.0000x reference)
//
#include <hip/hip_runtime.h>

typedef short v8s __attribute__((ext_vector_type(8)));
typedef float v4f __attribute__((ext_vector_type(4)));

#define LOG2E 1.44269504088896340736f

// ---- d_ws layout (bytes) ----
#define WS_FBF_T 0u          // u16 [8][4096][64]  f transposed (n-major, MFMA rows)
#define WS_FVP   4194304u    // u16 [8][64][4096]  f c-major, per-32 key-permuted cols
#define WS_G     8388608u    // f32 [8][4096]      row squared-norms
#define WS_BMAX  8519680u    // f32 [8][64]        per-chunk partial max of g
#define WS_LSUM  8521728u    // f32 [2][8][4096]   per-split row softmax denominators
#define WS_NEED  8783872u

__device__ __forceinline__ unsigned short f2bf_rne(float f) {
  unsigned int u = __builtin_bit_cast(unsigned int, f);
  u += 0x7FFFu + ((u >> 16) & 1u);
  return (unsigned short)(u >> 16);
}

__device__ __forceinline__ unsigned int pack_hi16(float hi, float lo) {
#if defined(__has_builtin) && __has_builtin(__builtin_amdgcn_perm)
  return __builtin_amdgcn_perm(__builtin_bit_cast(unsigned int, hi),
                               __builtin_bit_cast(unsigned int, lo), 0x07060302u);
#else
  return (__builtin_bit_cast(unsigned int, hi) & 0xFFFF0000u) |
         (__builtin_bit_cast(unsigned int, lo) >> 16);
#endif
}

// ============ pre-pass (R7 form, proven) ============
__global__ __launch_bounds__(256) void prep_kernel(
    const float* __restrict__ x, unsigned short* __restrict__ fbf_t,
    unsigned short* __restrict__ fvp, float* __restrict__ g, float* __restrict__ bmax) {
  __shared__ float red[4][64];
  const int t = threadIdx.x;
  const int b = blockIdx.x & 7, ch = blockIdx.x >> 3;
  const int n0 = ch << 6, nn = t & 63, n = n0 + nn, cg = t >> 6;

  const int kin = nn & 31;
  const int slot = (kin < 16) ? (((kin >> 2) << 3) + (kin & 3))
                              : ((((kin - 16) >> 2) << 3) + ((kin - 16) & 3) + 4);
  const int ncol = (n & ~31) + slot;

  float sq = 0.f;
  unsigned short w[16];
#pragma unroll
  for (int j = 0; j < 16; ++j) {
    const int c = cg * 16 + j;
    float v = x[((size_t)(b * 64 + c) << 12) + n];
    sq = __builtin_fmaf(v, v, sq);
    w[j] = f2bf_rne(v);
  }
  unsigned short* ft = fbf_t + ((size_t)b << 18) + (size_t)n * 64 + cg * 16;
  *(v8s*)ft = *(v8s*)&w[0];
  *(v8s*)(ft + 8) = *(v8s*)&w[8];
#pragma unroll
  for (int j = 0; j < 16; ++j)
    fvp[((size_t)(b * 64 + cg * 16 + j) << 12) + ncol] = w[j];

  red[cg][nn] = sq;
  __syncthreads();
  if (t < 64) {
    float tot = (red[0][t] + red[1][t]) + (red[2][t] + red[3][t]);
    g[b * 4096 + n0 + t] = tot;
    float m = tot;
    m = fmaxf(m, __shfl_xor(m, 1, 64));
    m = fmaxf(m, __shfl_xor(m, 2, 64));
    m = fmaxf(m, __shfl_xor(m, 4, 64));
    m = fmaxf(m, __shfl_xor(m, 8, 64));
    m = fmaxf(m, __shfl_xor(m, 16, 64));
    m = fmaxf(m, __shfl_xor(m, 32, 64));
    if (t == 0) bmax[b * 64 + ch] = m;
  }
}

// ============ main: Qb=256, key-split s=2, atomicAdd partial O^T into d_out ============
// grid 256 = (b 8) x (qt 16) x (s 2). 512 thr = 4 qg (64 q) x 2 kg (64 keys).
// Fixed-bound softmax => split partials merge by plain addition (same msc both splits).
// d_out must be zeroed before launch; final_norm normalizes + adds residual.
__global__ __launch_bounds__(512, 2) void chanattn_main(
    const unsigned short* __restrict__ fbf_t, const unsigned short* __restrict__ fvp,
    const float* __restrict__ g, const float* __restrict__ bmax,
    float* __restrict__ lws, float* __restrict__ out) {
  // dbuf p (+p*17920 u16): sKt u16[128][72] ; sVc u16[64][136] @+9216 u16
  // post-loop overlay: Obuf f32[64][257] @0 (65792 B); lred f32[4*4*16][2] @71680
  __shared__ __align__(16) unsigned char smem[73728];
  unsigned short* sKtB = (unsigned short*)smem;
  unsigned short* sVcB = (unsigned short*)(smem + 18432);
  float* lred = (float*)(smem + 71680);
  const int BUF = 17920;

  const int tid = threadIdx.x;
  const int wave = tid >> 6, lane = tid & 63, quad = lane >> 4, l15 = lane & 15;
  const int qg = wave >> 1, kg = wave & 1;
  const int b = blockIdx.x & 7, qt = (blockIdx.x >> 3) & 15, sp = blockIdx.x >> 7;
  const int k00 = sp << 11;   // split key base

  const unsigned short* fT = fbf_t + ((size_t)b << 18);  // [n][c]
  const unsigned short* fV = fvp + ((size_t)b << 18);    // [c][n'] permuted

  const int sKey = tid >> 3, sC = (tid & 7) << 3;   // K staging: key row, 8 c
  const int vC = tid >> 4, vK = (tid & 15) << 3;    // V staging: c row, 8 keys

  // batch gmax
  float gm = bmax[b * 64 + lane];
  gm = fmaxf(gm, __shfl_xor(gm, 1, 64));
  gm = fmaxf(gm, __shfl_xor(gm, 2, 64));
  gm = fmaxf(gm, __shfl_xor(gm, 4, 64));
  gm = fmaxf(gm, __shfl_xor(gm, 8, 64));
  gm = fmaxf(gm, __shfl_xor(gm, 16, 64));
  gm = fmaxf(gm, __shfl_xor(gm, 32, 64));
  float gq[4];
#pragma unroll
  for (int jq = 0; jq < 4; ++jq)
    gq[jq] = g[b * 4096 + qt * 256 + qg * 64 + jq * 16 + l15];

  // ---- stage 256-row Q tile across BOTH buffers' sKt ----
#pragma unroll
  for (int i = 0; i < 4; ++i) {
    int row = sKey + i * 64;
    *(v8s*)&sKtB[(row >> 7) * BUF + (row & 127) * 72 + sC] =
        *(const v8s*)&fT[(size_t)(qt * 256 + row) * 64 + sC];
  }
  // issue K/V tile-0 loads
  v8s pfk[2], pfv[2];
#pragma unroll
  for (int i = 0; i < 2; ++i)
    pfk[i] = *(const v8s*)&fT[(size_t)(k00 + sKey + i * 64) * 64 + sC];
#pragma unroll
  for (int i = 0; i < 2; ++i)
    pfv[i] = *(const v8s*)&fV[(size_t)(vC + i * 32) * 4096 + k00 + vK];

  __syncthreads();
  v8s bQ[4][2];   // static Q B-frags, rows qg*64 + jq*16 + l15 (buf by row>>7)
#pragma unroll
  for (int jq = 0; jq < 4; ++jq) {
    int row = qg * 64 + jq * 16 + l15;
#pragma unroll
    for (int cs = 0; cs < 2; ++cs)
      bQ[jq][cs] =
          *(const v8s*)&sKtB[(row >> 7) * BUF + (row & 127) * 72 + cs * 32 + quad * 8];
  }
  float msc[4];
#pragma unroll
  for (int jq = 0; jq < 4; ++jq) msc[jq] = __builtin_sqrtf(gq[jq] * gm) * LOG2E;
  __syncthreads();

  // write tile 0 -> buf0; issue tile-1 loads
#pragma unroll
  for (int i = 0; i < 2; ++i)
    *(v8s*)&sKtB[(sKey + i * 64) * 72 + sC] = pfk[i];
#pragma unroll
  for (int i = 0; i < 2; ++i)
    *(v8s*)&sVcB[(vC + i * 32) * 136 + vK] = pfv[i];
#pragma unroll
  for (int i = 0; i < 2; ++i)
    pfk[i] = *(const v8s*)&fT[(size_t)(k00 + 128 + sKey + i * 64) * 64 + sC];
#pragma unroll
  for (int i = 0; i < 2; ++i)
    pfv[i] = *(const v8s*)&fV[(size_t)(vC + i * 32) * 4096 + k00 + 128 + vK];

  v4f oacc[4][4];   // [jq][ct]: unnormalized O^T, col=q(l15), row=c(quad*4+r)
  float rsum[4];
#pragma unroll
  for (int jq = 0; jq < 4; ++jq) {
    rsum[jq] = 0.f;
#pragma unroll
    for (int ct = 0; ct < 4; ++ct) oacc[jq][ct] = (v4f){0.f, 0.f, 0.f, 0.f};
  }

  for (int kt = 0; kt < 16; ++kt) {
    __syncthreads();
    const int po = (kt & 1) * BUF;
    const int pn = ((kt & 1) ^ 1) * BUF;

    // frag reads: this wave's 64 keys = 2 chunks of 32
    v8s aK[2][2][2];   // [ch][t][cs]
#pragma unroll
    for (int ch = 0; ch < 2; ++ch)
#pragma unroll
      for (int t = 0; t < 2; ++t)
#pragma unroll
        for (int cs = 0; cs < 2; ++cs)
          aK[ch][t][cs] = *(const v8s*)&sKtB[po + (kg * 64 + ch * 32 + t * 16 + l15) * 72 +
                                             cs * 32 + quad * 8];
    v8s aV[2][4];
#pragma unroll
    for (int ch = 0; ch < 2; ++ch)
#pragma unroll
      for (int ct = 0; ct < 4; ++ct)
        aV[ch][ct] = *(const v8s*)&sVcB[po + (ct * 16 + l15) * 136 + kg * 64 + ch * 32 +
                                        quad * 8];

    // ---- chunk 0 compute (MFMA in flight before staging/vm waits) ----
#pragma unroll
    for (int jq = 0; jq < 4; ++jq) {
      v4f s0 = (v4f){0.f, 0.f, 0.f, 0.f}, s1 = (v4f){0.f, 0.f, 0.f, 0.f};
#pragma unroll
      for (int cs = 0; cs < 2; ++cs) {
        s0 = __builtin_amdgcn_mfma_f32_16x16x32_bf16(aK[0][0][cs], bQ[jq][cs], s0, 0, 0, 0);
        s1 = __builtin_amdgcn_mfma_f32_16x16x32_bf16(aK[0][1][cs], bQ[jq][cs], s1, 0, 0, 0);
      }
      float p0[4], p1[4];
#pragma unroll
      for (int r = 0; r < 4; ++r) {
        p0[r] = __builtin_amdgcn_exp2f(__builtin_fmaf(s0[r], LOG2E, -msc[jq]));
        p1[r] = __builtin_amdgcn_exp2f(__builtin_fmaf(s1[r], LOG2E, -msc[jq]));
      }
      rsum[jq] += ((p0[0] + p0[1]) + (p0[2] + p0[3])) +
                  ((p1[0] + p1[1]) + (p1[2] + p1[3]));
      uint4 up;
      up.x = pack_hi16(p0[1], p0[0]);
      up.y = pack_hi16(p0[3], p0[2]);
      up.z = pack_hi16(p1[1], p1[0]);
      up.w = pack_hi16(p1[3], p1[2]);
      v8s bp = __builtin_bit_cast(v8s, up);
#pragma unroll
      for (int ct = 0; ct < 4; ++ct)
        oacc[jq][ct] =
            __builtin_amdgcn_mfma_f32_16x16x32_bf16(aV[0][ct], bp, oacc[jq][ct], 0, 0, 0);
    }

    // ---- staging writes for tile kt+1, then issue tile kt+2 loads ----
    if (kt < 15) {
#pragma unroll
      for (int i = 0; i < 2; ++i)
        *(v8s*)&sKtB[pn + (sKey + i * 64) * 72 + sC] = pfk[i];
#pragma unroll
      for (int i = 0; i < 2; ++i)
        *(v8s*)&sVcB[pn + (vC + i * 32) * 136 + vK] = pfv[i];
    }
    if (kt < 14) {
      const int k0 = k00 + ((kt + 2) << 7);
#pragma unroll
      for (int i = 0; i < 2; ++i)
        pfk[i] = *(const v8s*)&fT[(size_t)(k0 + sKey + i * 64) * 64 + sC];
#pragma unroll
      for (int i = 0; i < 2; ++i)
        pfv[i] = *(const v8s*)&fV[(size_t)(vC + i * 32) * 4096 + k0 + vK];
    }

    // ---- chunk 1 compute ----
#pragma unroll
    for (int jq = 0; jq < 4; ++jq) {
      v4f s0 = (v4f){0.f, 0.f, 0.f, 0.f}, s1 = (v4f){0.f, 0.f, 0.f, 0.f};
#pragma unroll
      for (int cs = 0; cs < 2; ++cs) {
        s0 = __builtin_amdgcn_mfma_f32_16x16x32_bf16(aK[1][0][cs], bQ[jq][cs], s0, 0, 0, 0);
        s1 = __builtin_amdgcn_mfma_f32_16x16x32_bf16(aK[1][1][cs], bQ[jq][cs], s1, 0, 0, 0);
      }
      float p0[4], p1[4];
#pragma unroll
      for (int r = 0; r < 4; ++r) {
        p0[r] = __builtin_amdgcn_exp2f(__builtin_fmaf(s0[r], LOG2E, -msc[jq]));
        p1[r] = __builtin_amdgcn_exp2f(__builtin_fmaf(s1[r], LOG2E, -msc[jq]));
      }
      rsum[jq] += ((p0[0] + p0[1]) + (p0[2] + p0[3])) +
                  ((p1[0] + p1[1]) + (p1[2] + p1[3]));
      uint4 up;
      up.x = pack_hi16(p0[1], p0[0]);
      up.y = pack_hi16(p0[3], p0[2]);
      up.z = pack_hi16(p1[1], p1[0]);
      up.w = pack_hi16(p1[3], p1[2]);
      v8s bp = __builtin_bit_cast(v8s, up);
#pragma unroll
      for (int ct = 0; ct < 4; ++ct)
        oacc[jq][ct] =
            __builtin_amdgcn_mfma_f32_16x16x32_bf16(aV[1][ct], bp, oacc[jq][ct], 0, 0, 0);
    }
  }

  // ---- l: fold over quads, merge kg, write per-split (no normalization here) ----
#pragma unroll
  for (int jq = 0; jq < 4; ++jq) {
    float s = rsum[jq];
    s += __shfl_xor(s, 16, 64);
    s += __shfl_xor(s, 32, 64);
    rsum[jq] = s;
  }
  __syncthreads();   // K-loop LDS reads done -> reuse smem
  if (quad == 0) {
#pragma unroll
    for (int jq = 0; jq < 4; ++jq)
      lred[((qg * 4 + jq) * 16 + l15) * 2 + kg] = rsum[jq];
  }
  __syncthreads();
  if (kg == 0 && quad == 0) {
#pragma unroll
    for (int jq = 0; jq < 4; ++jq) {
      int i = (qg * 4 + jq) * 16 + l15;
      lws[sp * 32768 + b * 4096 + qt * 256 + i] = lred[i * 2] + lred[i * 2 + 1];
    }
  }

  // ---- merge kg partials in LDS (Obuf f32[64][257]), atomicAdd to d_out ----
  float* Obuf = (float*)smem;
#pragma unroll
  for (int round = 0; round < 2; ++round) {
    if (kg == round) {
#pragma unroll
      for (int jq = 0; jq < 4; ++jq)
#pragma unroll
        for (int ct = 0; ct < 4; ++ct)
#pragma unroll
          for (int r = 0; r < 4; ++r) {
            float* p = &Obuf[(ct * 16 + quad * 4 + r) * 257 + qg * 64 + jq * 16 + l15];
            if (round == 0) *p = oacc[jq][ct][r]; else *p += oacc[jq][ct][r];
          }
    }
    __syncthreads();
  }
#pragma unroll
  for (int k = 0; k < 32; ++k) {
    int idx = tid + k * 512;          // 0..16383 over (c, q)
    int c = idx >> 8, q = idx & 255;
    atomicAdd(out + ((size_t)(b * 64 + c) << 12) + qt * 256 + q, Obuf[c * 257 + q]);
  }
}

// ============ final: out = x + Osum * rcp(l0+l1) ============
__global__ __launch_bounds__(256) void final_norm(
    const float* __restrict__ x, const float* __restrict__ lws, float* __restrict__ out) {
  const int b = blockIdx.x & 7, seg = blockIdx.x >> 3;   // 32 segs of 2 c-rows
  const int t = threadIdx.x;
#pragma unroll
  for (int j = 0; j < 8; ++j) {
    int fl = seg * 2048 + j * 256 + t;     // float4 index within batch [64][1024]
    int c = fl >> 10, n4 = (fl & 1023) << 2;
    size_t gidx = ((size_t)(b * 64 + c) << 12) + n4;
    float4 o = *(const float4*)(out + gidx);
    float4 xv = *(const float4*)(x + gidx);
    float4 l0 = *(const float4*)(lws + b * 4096 + n4);
    float4 l1 = *(const float4*)(lws + 32768 + b * 4096 + n4);
    float4 rv;
    rv.x = xv.x + o.x * __builtin_amdgcn_rcpf(l0.x + l1.x);
    rv.y = xv.y + o.y * __builtin_amdgcn_rcpf(l0.y + l1.y);
    rv.z = xv.z + o.z * __builtin_amdgcn_rcpf(l0.z + l1.z);
    rv.w = xv.w + o.w * __builtin_amdgcn_rcpf(l0.w + l1.w);
    *(float4*)(out + gidx) = rv;
  }
}

// ============ fallback (R1 kernel, proven correct) if ws too small ============
__global__ __launch_bounds__(512) void
chanattn_fallback(const float* __restrict__ x, float* __restrict__ out) {
  __shared__ __align__(16) unsigned char smem[54272];
  unsigned short* sKt = (unsigned short*)smem;
  unsigned short* sVc = (unsigned short*)(smem + 18432);
  unsigned short* sP  = (unsigned short*)(smem + 35840);
  const int tid = threadIdx.x;
  const int wave = tid >> 6, lane = tid & 63, quad = lane >> 4, l15 = lane & 15;
  const int b = blockIdx.x & 7, qt = blockIdx.x >> 3;
  const float* fb = x + (size_t)b * (64 * 4096);
  const int skey = tid & 127, sc0 = (tid >> 7) << 4;
  {
    float vq[16];
#pragma unroll
    for (int j = 0; j < 16; ++j) vq[j] = fb[(sc0 + j) * 4096 + qt * 128 + skey];
    unsigned short us[16];
#pragma unroll
    for (int j = 0; j < 16; ++j) us[j] = f2bf_rne(vq[j]);
#pragma unroll
    for (int h = 0; h < 2; ++h) {
      v8s t;
#pragma unroll
      for (int j = 0; j < 8; ++j) t[j] = (short)us[h * 8 + j];
      *(v8s*)&sKt[skey * 72 + sc0 + h * 8] = t;
    }
  }
  float vk[16];
#pragma unroll
  for (int j = 0; j < 16; ++j) vk[j] = fb[(sc0 + j) * 4096 + skey];
  __syncthreads();
  v8s aq[2];
#pragma unroll
  for (int cs = 0; cs < 2; ++cs)
    aq[cs] = *(const v8s*)&sKt[(wave * 16 + l15) * 72 + cs * 32 + quad * 8];
  __syncthreads();
  v4f oacc[4];
#pragma unroll
  for (int ct = 0; ct < 4; ++ct) oacc[ct] = (v4f){0.f, 0.f, 0.f, 0.f};
  float m_run[4], l_run[4];
#pragma unroll
  for (int r = 0; r < 4; ++r) { m_run[r] = -3.0e38f; l_run[r] = 0.f; }
  unsigned short* sPw = sP + wave * (16 * 72);
  for (int kt = 0; kt < 32; ++kt) {
    {
      unsigned short us[16];
#pragma unroll
      for (int j = 0; j < 16; ++j) us[j] = f2bf_rne(vk[j]);
#pragma unroll
      for (int h = 0; h < 2; ++h) {
        v8s t;
#pragma unroll
        for (int j = 0; j < 8; ++j) t[j] = (short)us[h * 8 + j];
        *(v8s*)&sKt[skey * 72 + sc0 + h * 8] = t;
      }
#pragma unroll
      for (int j = 0; j < 16; ++j) sVc[(sc0 + j) * 136 + skey] = us[j];
    }
    __syncthreads();
    if (kt + 1 < 32) {
      const int m0 = (kt + 1) * 128;
#pragma unroll
      for (int j = 0; j < 16; ++j) vk[j] = fb[(sc0 + j) * 4096 + m0 + skey];
    }
    v4f sacc[8];
#pragma unroll
    for (int t = 0; t < 8; ++t) {
      v4f acc = (v4f){0.f, 0.f, 0.f, 0.f};
#pragma unroll
      for (int cs = 0; cs < 2; ++cs) {
        v8s bf = *(const v8s*)&sKt[(t * 16 + l15) * 72 + cs * 32 + quad * 8];
        acc = __builtin_amdgcn_mfma_f32_16x16x32_bf16(aq[cs], bf, acc, 0, 0, 0);
      }
      sacc[t] = acc;
    }
    float alpha[4], msc[4], rsum[4];
#pragma unroll
    for (int r = 0; r < 4; ++r) {
      float mv = sacc[0][r];
#pragma unroll
      for (int t = 1; t < 8; ++t) mv = fmaxf(mv, sacc[t][r]);
      mv = fmaxf(mv, __shfl_xor(mv, 8, 64));
      mv = fmaxf(mv, __shfl_xor(mv, 4, 64));
      mv = fmaxf(mv, __shfl_xor(mv, 2, 64));
      mv = fmaxf(mv, __shfl_xor(mv, 1, 64));
      float mnew = fmaxf(m_run[r], mv);
      alpha[r] = __builtin_amdgcn_exp2f((m_run[r] - mnew) * LOG2E);
      m_run[r] = mnew;
      msc[r] = mnew * LOG2E;
      l_run[r] *= alpha[r];
      rsum[r] = 0.f;
    }
#pragma unroll
    for (int ct = 0; ct < 4; ++ct)
#pragma unroll
      for (int r = 0; r < 4; ++r) oacc[ct][r] *= alpha[r];
#pragma unroll
    for (int half = 0; half < 2; ++half) {
#pragma unroll
      for (int t = half * 4; t < half * 4 + 4; ++t)
#pragma unroll
        for (int r = 0; r < 4; ++r) {
          float p = __builtin_amdgcn_exp2f(__builtin_fmaf(sacc[t][r], LOG2E, -msc[r]));
          rsum[r] += p;
          sPw[(quad * 4 + r) * 72 + (t - half * 4) * 16 + l15] = f2bf_rne(p);
        }
      asm volatile("s_waitcnt lgkmcnt(0)" ::: "memory");
#pragma unroll
      for (int ms = 0; ms < 2; ++ms) {
        v8s af = *(const v8s*)&sPw[l15 * 72 + ms * 32 + quad * 8];
#pragma unroll
        for (int ct = 0; ct < 4; ++ct) {
          v8s bf = *(const v8s*)&sVc[(ct * 16 + l15) * 136 + (half * 2 + ms) * 32 + quad * 8];
          oacc[ct] = __builtin_amdgcn_mfma_f32_16x16x32_bf16(af, bf, oacc[ct], 0, 0, 0);
        }
      }
      asm volatile("s_waitcnt lgkmcnt(0)" ::: "memory");
    }
#pragma unroll
    for (int r = 0; r < 4; ++r) {
      float s = rsum[r];
      s += __shfl_xor(s, 8, 64);
      s += __shfl_xor(s, 4, 64);
      s += __shfl_xor(s, 2, 64);
      s += __shfl_xor(s, 1, 64);
      l_run[r] += s;
    }
    __syncthreads();
  }
  float inv[4];
#pragma unroll
  for (int r = 0; r < 4; ++r) inv[r] = __builtin_amdgcn_rcpf(l_run[r]);
  float* sOt = (float*)smem;
#pragma unroll
  for (int ct = 0; ct < 4; ++ct)
#pragma unroll
    for (int r = 0; r < 4; ++r)
      sOt[(ct * 16 + l15) * 132 + wave * 16 + quad * 4 + r] = oacc[ct][r] * inv[r];
  __syncthreads();
#pragma unroll
  for (int j = 0; j < 4; ++j) {
    int idx = tid + j * 512;
    int nv = idx & 31, c = idx >> 5;
    float4 o = *(const float4*)&sOt[c * 132 + nv * 4];
    size_t gaddr = (size_t)b * (64 * 4096) + (size_t)c * 4096 + (size_t)(qt * 128 + nv * 4);
    float4 xv = *(const float4*)(x + gaddr);
    float4 res = make_float4(xv.x + o.x, xv.y + o.y, xv.z + o.z, xv.w + o.w);
    *(float4*)(out + gaddr) = res;
  }
}

extern "C" void kernel_launch(void* const* d_in, const int* in_sizes, int n_in,
                              void* d_out, int out_size, void* d_ws, size_t ws_size,
                              hipStream_t stream) {
  const float* xin = (const float*)d_in[0];
  float* out = (float*)d_out;
  if (ws_size >= (size_t)WS_NEED) {
    unsigned short* fbf_t = (unsigned short*)((char*)d_ws + WS_FBF_T);
    unsigned short* fvp = (unsigned short*)((char*)d_ws + WS_FVP);
    float* g = (float*)((char*)d_ws + WS_G);
    float* bmax = (float*)((char*)d_ws + WS_BMAX);
    float* lws = (float*)((char*)d_ws + WS_LSUM);
    hipMemsetAsync(d_out, 0, (size_t)out_size * sizeof(float), stream);
    prep_kernel<<<dim3(512), dim3(256), 0, stream>>>(xin, fbf_t, fvp, g, bmax);
    chanattn_main<<<dim3(256), dim3(512), 0, stream>>>(fbf_t, fvp, g, bmax, lws, out);
    final_norm<<<dim3(256), dim3(256), 0, stream>>>(xin, lws, out);
  } else {
    chanattn_fallback<<<dim3(256), dim3(512), 0, stream>>>(xin, out);
  }
}

// Round 10
// 103.414 us; speedup vs baseline: 1.2118x; 1.2118x over previous
//
#include <hip/hip_runtime.h>

typedef short v8s __attribute__((ext_vector_type(8)));
typedef float v4f __attribute__((ext_vector_type(4)));

#define LOG2E 1.44269504088896340736f

// ---- d_ws layout (bytes) ----
#define WS_FBF_T 0u          // u16 [8][4096][64]  f transposed (n-major, MFMA rows)
#define WS_FVP   4194304u    // u16 [8][64][4096]  f c-major, per-32 key-permuted cols
#define WS_G     8388608u    // f32 [8][4096]      row squared-norms
#define WS_BMAX  8519680u    // f32 [8][64]        per-chunk partial max of g
#define WS_NEED  8521728u

__device__ __forceinline__ unsigned short f2bf_rne(float f) {
  unsigned int u = __builtin_bit_cast(unsigned int, f);
  u += 0x7FFFu + ((u >> 16) & 1u);
  return (unsigned short)(u >> 16);
}

__device__ __forceinline__ unsigned int pack_hi16(float hi, float lo) {
#if defined(__has_builtin) && __has_builtin(__builtin_amdgcn_perm)
  return __builtin_amdgcn_perm(__builtin_bit_cast(unsigned int, hi),
                               __builtin_bit_cast(unsigned int, lo), 0x07060302u);
#else
  return (__builtin_bit_cast(unsigned int, hi) & 0xFFFF0000u) |
         (__builtin_bit_cast(unsigned int, lo) >> 16);
#endif
}

// ============ pre-pass (R7 form, proven) — batch = blockIdx>>6 for linear-fill XCD affinity ============
__global__ __launch_bounds__(256) void prep_kernel(
    const float* __restrict__ x, unsigned short* __restrict__ fbf_t,
    unsigned short* __restrict__ fvp, float* __restrict__ g, float* __restrict__ bmax) {
  __shared__ float red[4][64];
  const int t = threadIdx.x;
  const int b = blockIdx.x >> 6, ch = blockIdx.x & 63;   // blocks 0..63 -> batch 0
  const int n0 = ch << 6, nn = t & 63, n = n0 + nn, cg = t >> 6;

  const int kin = nn & 31;
  const int slot = (kin < 16) ? (((kin >> 2) << 3) + (kin & 3))
                              : ((((kin - 16) >> 2) << 3) + ((kin - 16) & 3) + 4);
  const int ncol = (n & ~31) + slot;

  float sq = 0.f;
  unsigned short w[16];
#pragma unroll
  for (int j = 0; j < 16; ++j) {
    const int c = cg * 16 + j;
    float v = x[((size_t)(b * 64 + c) << 12) + n];
    sq = __builtin_fmaf(v, v, sq);
    w[j] = f2bf_rne(v);
  }
  unsigned short* ft = fbf_t + ((size_t)b << 18) + (size_t)n * 64 + cg * 16;
  *(v8s*)ft = *(v8s*)&w[0];
  *(v8s*)(ft + 8) = *(v8s*)&w[8];
#pragma unroll
  for (int j = 0; j < 16; ++j)
    fvp[((size_t)(b * 64 + cg * 16 + j) << 12) + ncol] = w[j];

  red[cg][nn] = sq;
  __syncthreads();
  if (t < 64) {
    float tot = (red[0][t] + red[1][t]) + (red[2][t] + red[3][t]);
    g[b * 4096 + n0 + t] = tot;
    float m = tot;
    m = fmaxf(m, __shfl_xor(m, 1, 64));
    m = fmaxf(m, __shfl_xor(m, 2, 64));
    m = fmaxf(m, __shfl_xor(m, 4, 64));
    m = fmaxf(m, __shfl_xor(m, 8, 64));
    m = fmaxf(m, __shfl_xor(m, 16, 64));
    m = fmaxf(m, __shfl_xor(m, 32, 64));
    if (t == 0) bmax[b * 64 + ch] = m;
  }
}

// ============ main: R5 proven structure; ONLY change = batch swizzle blockIdx>>5 ============
// If dispatch is linear-fill (blocks 0..31 -> XCD0), each XCD now touches ONE
// batch (1 MB working set < 4 MB L2) instead of all 8 (8 MB -> LLC thrash).
__global__ __launch_bounds__(512, 2) void chanattn_main(
    const float* __restrict__ x, const unsigned short* __restrict__ fbf_t,
    const unsigned short* __restrict__ fvp, const float* __restrict__ g,
    const float* __restrict__ bmax, float* __restrict__ out) {
  __shared__ __align__(16) unsigned char smem[73728];
  unsigned short* sKtB = (unsigned short*)smem;
  unsigned short* sVcB = (unsigned short*)(smem + 18432);
  float* lred = (float*)(smem + 71680);
  const int BUF = 17920;

  const int tid = threadIdx.x;
  const int wave = tid >> 6, lane = tid & 63, quad = lane >> 4, l15 = lane & 15;
  const int qg = wave >> 2, kg = wave & 3;
  const int b = blockIdx.x >> 5, qt = blockIdx.x & 31;   // THE experiment

  const unsigned short* fT = fbf_t + ((size_t)b << 18);  // [n][c]
  const unsigned short* fV = fvp + ((size_t)b << 18);    // [c][n'] permuted

  const int sKey = tid >> 3, sC = (tid & 7) << 3;
  const int vC = tid >> 4, vK = (tid & 15) << 3;

  float gm = bmax[b * 64 + lane];
  gm = fmaxf(gm, __shfl_xor(gm, 1, 64));
  gm = fmaxf(gm, __shfl_xor(gm, 2, 64));
  gm = fmaxf(gm, __shfl_xor(gm, 4, 64));
  gm = fmaxf(gm, __shfl_xor(gm, 8, 64));
  gm = fmaxf(gm, __shfl_xor(gm, 16, 64));
  gm = fmaxf(gm, __shfl_xor(gm, 32, 64));
  float gq[4];
#pragma unroll
  for (int jq = 0; jq < 4; ++jq)
    gq[jq] = g[b * 4096 + qt * 128 + qg * 64 + jq * 16 + l15];

  // stage Q tile into buf0 sKt
#pragma unroll
  for (int i = 0; i < 2; ++i)
    *(v8s*)&sKtB[(sKey + i * 64) * 72 + sC] =
        *(const v8s*)&fT[(size_t)(qt * 128 + sKey + i * 64) * 64 + sC];
  // issue tile-0 loads
  v8s pfk[2], pfv[2];
#pragma unroll
  for (int i = 0; i < 2; ++i)
    pfk[i] = *(const v8s*)&fT[(size_t)(sKey + i * 64) * 64 + sC];
#pragma unroll
  for (int i = 0; i < 2; ++i)
    pfv[i] = *(const v8s*)&fV[(size_t)(vC + i * 32) * 4096 + vK];

  __syncthreads();
  v8s bQ[4][2];
#pragma unroll
  for (int jq = 0; jq < 4; ++jq)
#pragma unroll
    for (int cs = 0; cs < 2; ++cs)
      bQ[jq][cs] = *(const v8s*)&sKtB[(qg * 64 + jq * 16 + l15) * 72 + cs * 32 + quad * 8];
  float msc[4];
#pragma unroll
  for (int jq = 0; jq < 4; ++jq) msc[jq] = __builtin_sqrtf(gq[jq] * gm) * LOG2E;
  __syncthreads();

  // write tile 0 -> buf0 (fvp pre-permuted: verbatim v8s); issue tile-1 loads
#pragma unroll
  for (int i = 0; i < 2; ++i)
    *(v8s*)&sKtB[(sKey + i * 64) * 72 + sC] = pfk[i];
#pragma unroll
  for (int i = 0; i < 2; ++i)
    *(v8s*)&sVcB[(vC + i * 32) * 136 + vK] = pfv[i];
#pragma unroll
  for (int i = 0; i < 2; ++i)
    pfk[i] = *(const v8s*)&fT[(size_t)(128 + sKey + i * 64) * 64 + sC];
#pragma unroll
  for (int i = 0; i < 2; ++i)
    pfv[i] = *(const v8s*)&fV[(size_t)(vC + i * 32) * 4096 + 128 + vK];

  v4f oacc[4][4];
  float rsum[4];
#pragma unroll
  for (int ct = 0; ct < 4; ++ct)
#pragma unroll
    for (int jq = 0; jq < 4; ++jq) oacc[ct][jq] = (v4f){0.f, 0.f, 0.f, 0.f};
#pragma unroll
  for (int jq = 0; jq < 4; ++jq) rsum[jq] = 0.f;

  for (int kt = 0; kt < 32; ++kt) {
    __syncthreads();
    const int po = (kt & 1) * BUF;
    const int pn = ((kt & 1) ^ 1) * BUF;

    v8s aK[2][2];
#pragma unroll
    for (int t = 0; t < 2; ++t)
#pragma unroll
      for (int cs = 0; cs < 2; ++cs)
        aK[t][cs] =
            *(const v8s*)&sKtB[po + (kg * 32 + t * 16 + l15) * 72 + cs * 32 + quad * 8];
    v8s aV[4];
#pragma unroll
    for (int ct = 0; ct < 4; ++ct)
      aV[ct] = *(const v8s*)&sVcB[po + (ct * 16 + l15) * 136 + kg * 32 + quad * 8];

    // jq=0 first: MFMA in flight before staging/vm waits
    {
      const int jq = 0;
      v4f s0 = (v4f){0.f, 0.f, 0.f, 0.f}, s1 = (v4f){0.f, 0.f, 0.f, 0.f};
#pragma unroll
      for (int cs = 0; cs < 2; ++cs) {
        s0 = __builtin_amdgcn_mfma_f32_16x16x32_bf16(aK[0][cs], bQ[jq][cs], s0, 0, 0, 0);
        s1 = __builtin_amdgcn_mfma_f32_16x16x32_bf16(aK[1][cs], bQ[jq][cs], s1, 0, 0, 0);
      }
      float p0[4], p1[4];
#pragma unroll
      for (int r = 0; r < 4; ++r) {
        p0[r] = __builtin_amdgcn_exp2f(__builtin_fmaf(s0[r], LOG2E, -msc[jq]));
        p1[r] = __builtin_amdgcn_exp2f(__builtin_fmaf(s1[r], LOG2E, -msc[jq]));
      }
      rsum[jq] += ((p0[0] + p0[1]) + (p0[2] + p0[3])) +
                  ((p1[0] + p1[1]) + (p1[2] + p1[3]));
      uint4 up;
      up.x = pack_hi16(p0[1], p0[0]);
      up.y = pack_hi16(p0[3], p0[2]);
      up.z = pack_hi16(p1[1], p1[0]);
      up.w = pack_hi16(p1[3], p1[2]);
      v8s bp = __builtin_bit_cast(v8s, up);
#pragma unroll
      for (int ct = 0; ct < 4; ++ct)
        oacc[ct][jq] =
            __builtin_amdgcn_mfma_f32_16x16x32_bf16(aV[ct], bp, oacc[ct][jq], 0, 0, 0);
    }

    if (kt < 31) {
#pragma unroll
      for (int i = 0; i < 2; ++i)
        *(v8s*)&sKtB[pn + (sKey + i * 64) * 72 + sC] = pfk[i];
#pragma unroll
      for (int i = 0; i < 2; ++i)
        *(v8s*)&sVcB[pn + (vC + i * 32) * 136 + vK] = pfv[i];
    }
    if (kt < 30) {
      const int k0 = (kt + 2) << 7;
#pragma unroll
      for (int i = 0; i < 2; ++i)
        pfk[i] = *(const v8s*)&fT[(size_t)(k0 + sKey + i * 64) * 64 + sC];
#pragma unroll
      for (int i = 0; i < 2; ++i)
        pfv[i] = *(const v8s*)&fV[(size_t)(vC + i * 32) * 4096 + k0 + vK];
    }

#pragma unroll
    for (int jq = 1; jq < 4; ++jq) {
      v4f s0 = (v4f){0.f, 0.f, 0.f, 0.f}, s1 = (v4f){0.f, 0.f, 0.f, 0.f};
#pragma unroll
      for (int cs = 0; cs < 2; ++cs) {
        s0 = __builtin_amdgcn_mfma_f32_16x16x32_bf16(aK[0][cs], bQ[jq][cs], s0, 0, 0, 0);
        s1 = __builtin_amdgcn_mfma_f32_16x16x32_bf16(aK[1][cs], bQ[jq][cs], s1, 0, 0, 0);
      }
      float p0[4], p1[4];
#pragma unroll
      for (int r = 0; r < 4; ++r) {
        p0[r] = __builtin_amdgcn_exp2f(__builtin_fmaf(s0[r], LOG2E, -msc[jq]));
        p1[r] = __builtin_amdgcn_exp2f(__builtin_fmaf(s1[r], LOG2E, -msc[jq]));
      }
      rsum[jq] += ((p0[0] + p0[1]) + (p0[2] + p0[3])) +
                  ((p1[0] + p1[1]) + (p1[2] + p1[3]));
      uint4 up;
      up.x = pack_hi16(p0[1], p0[0]);
      up.y = pack_hi16(p0[3], p0[2]);
      up.z = pack_hi16(p1[1], p1[0]);
      up.w = pack_hi16(p1[3], p1[2]);
      v8s bp = __builtin_bit_cast(v8s, up);
#pragma unroll
      for (int ct = 0; ct < 4; ++ct)
        oacc[ct][jq] =
            __builtin_amdgcn_mfma_f32_16x16x32_bf16(aV[ct], bp, oacc[ct][jq], 0, 0, 0);
    }
  }

  // ---- epilogue ----
#pragma unroll
  for (int jq = 0; jq < 4; ++jq) {
    float s = rsum[jq];
    s += __shfl_xor(s, 16, 64);
    s += __shfl_xor(s, 32, 64);
    rsum[jq] = s;
  }
  if (quad == 0) {
#pragma unroll
    for (int jq = 0; jq < 4; ++jq)
      lred[(qg * 64 + jq * 16 + l15) * 4 + kg] = rsum[jq];
  }
  __syncthreads();
  float inv[4];
#pragma unroll
  for (int jq = 0; jq < 4; ++jq) {
    const float4 lv = *(const float4*)&lred[(qg * 64 + jq * 16 + l15) * 4];
    inv[jq] = __builtin_amdgcn_rcpf((lv.x + lv.y) + (lv.z + lv.w));
  }

  float* Obuf = (float*)smem;   // [2 qg][64 c][68 q]
#pragma unroll
  for (int round = 0; round < 4; ++round) {
    if (kg == round) {
#pragma unroll
      for (int ct = 0; ct < 4; ++ct)
#pragma unroll
        for (int jq = 0; jq < 4; ++jq)
#pragma unroll
          for (int r = 0; r < 4; ++r) {
            float val = oacc[ct][jq][r] * inv[jq];
            float* p = &Obuf[(qg * 64 + ct * 16 + quad * 4 + r) * 68 + jq * 16 + l15];
            if (round == 0) *p = val; else *p += val;
          }
    }
    __syncthreads();
  }
#pragma unroll
  for (int j = 0; j < 4; ++j) {
    int idx = tid + j * 512;
    int qg2 = idx >> 10, c = (idx >> 4) & 63, q4 = idx & 15;
    const float4 o = *(const float4*)&Obuf[(qg2 * 64 + c) * 68 + q4 * 4];
    size_t gidx = ((size_t)(b * 64 + c) << 12) + (unsigned)(qt * 128 + qg2 * 64 + q4 * 4);
    const float4 xv = *(const float4*)(x + gidx);
    float4 rv;
    rv.x = xv.x + o.x; rv.y = xv.y + o.y; rv.z = xv.z + o.z; rv.w = xv.w + o.w;
    *(float4*)(out + gidx) = rv;
  }
}

// ============ fallback (R1 kernel, proven correct) if ws too small ============
__global__ __launch_bounds__(512) void
chanattn_fallback(const float* __restrict__ x, float* __restrict__ out) {
  __shared__ __align__(16) unsigned char smem[54272];
  unsigned short* sKt = (unsigned short*)smem;
  unsigned short* sVc = (unsigned short*)(smem + 18432);
  unsigned short* sP  = (unsigned short*)(smem + 35840);
  const int tid = threadIdx.x;
  const int wave = tid >> 6, lane = tid & 63, quad = lane >> 4, l15 = lane & 15;
  const int b = blockIdx.x & 7, qt = blockIdx.x >> 3;
  const float* fb = x + (size_t)b * (64 * 4096);
  const int skey = tid & 127, sc0 = (tid >> 7) << 4;
  {
    float vq[16];
#pragma unroll
    for (int j = 0; j < 16; ++j) vq[j] = fb[(sc0 + j) * 4096 + qt * 128 + skey];
    unsigned short us[16];
#pragma unroll
    for (int j = 0; j < 16; ++j) us[j] = f2bf_rne(vq[j]);
#pragma unroll
    for (int h = 0; h < 2; ++h) {
      v8s t;
#pragma unroll
      for (int j = 0; j < 8; ++j) t[j] = (short)us[h * 8 + j];
      *(v8s*)&sKt[skey * 72 + sc0 + h * 8] = t;
    }
  }
  float vk[16];
#pragma unroll
  for (int j = 0; j < 16; ++j) vk[j] = fb[(sc0 + j) * 4096 + skey];
  __syncthreads();
  v8s aq[2];
#pragma unroll
  for (int cs = 0; cs < 2; ++cs)
    aq[cs] = *(const v8s*)&sKt[(wave * 16 + l15) * 72 + cs * 32 + quad * 8];
  __syncthreads();
  v4f oacc[4];
#pragma unroll
  for (int ct = 0; ct < 4; ++ct) oacc[ct] = (v4f){0.f, 0.f, 0.f, 0.f};
  float m_run[4], l_run[4];
#pragma unroll
  for (int r = 0; r < 4; ++r) { m_run[r] = -3.0e38f; l_run[r] = 0.f; }
  unsigned short* sPw = sP + wave * (16 * 72);
  for (int kt = 0; kt < 32; ++kt) {
    {
      unsigned short us[16];
#pragma unroll
      for (int j = 0; j < 16; ++j) us[j] = f2bf_rne(vk[j]);
#pragma unroll
      for (int h = 0; h < 2; ++h) {
        v8s t;
#pragma unroll
        for (int j = 0; j < 8; ++j) t[j] = (short)us[h * 8 + j];
        *(v8s*)&sKt[skey * 72 + sc0 + h * 8] = t;
      }
#pragma unroll
      for (int j = 0; j < 16; ++j) sVc[(sc0 + j) * 136 + skey] = us[j];
    }
    __syncthreads();
    if (kt + 1 < 32) {
      const int m0 = (kt + 1) * 128;
#pragma unroll
      for (int j = 0; j < 16; ++j) vk[j] = fb[(sc0 + j) * 4096 + m0 + skey];
    }
    v4f sacc[8];
#pragma unroll
    for (int t = 0; t < 8; ++t) {
      v4f acc = (v4f){0.f, 0.f, 0.f, 0.f};
#pragma unroll
      for (int cs = 0; cs < 2; ++cs) {
        v8s bf = *(const v8s*)&sKt[(t * 16 + l15) * 72 + cs * 32 + quad * 8];
        acc = __builtin_amdgcn_mfma_f32_16x16x32_bf16(aq[cs], bf, acc, 0, 0, 0);
      }
      sacc[t] = acc;
    }
    float alpha[4], msc[4], rsum[4];
#pragma unroll
    for (int r = 0; r < 4; ++r) {
      float mv = sacc[0][r];
#pragma unroll
      for (int t = 1; t < 8; ++t) mv = fmaxf(mv, sacc[t][r]);
      mv = fmaxf(mv, __shfl_xor(mv, 8, 64));
      mv = fmaxf(mv, __shfl_xor(mv, 4, 64));
      mv = fmaxf(mv, __shfl_xor(mv, 2, 64));
      mv = fmaxf(mv, __shfl_xor(mv, 1, 64));
      float mnew = fmaxf(m_run[r], mv);
      alpha[r] = __builtin_amdgcn_exp2f((m_run[r] - mnew) * LOG2E);
      m_run[r] = mnew;
      msc[r] = mnew * LOG2E;
      l_run[r] *= alpha[r];
      rsum[r] = 0.f;
    }
#pragma unroll
    for (int ct = 0; ct < 4; ++ct)
#pragma unroll
      for (int r = 0; r < 4; ++r) oacc[ct][r] *= alpha[r];
#pragma unroll
    for (int half = 0; half < 2; ++half) {
#pragma unroll
      for (int t = half * 4; t < half * 4 + 4; ++t)
#pragma unroll
        for (int r = 0; r < 4; ++r) {
          float p = __builtin_amdgcn_exp2f(__builtin_fmaf(sacc[t][r], LOG2E, -msc[r]));
          rsum[r] += p;
          sPw[(quad * 4 + r) * 72 + (t - half * 4) * 16 + l15] = f2bf_rne(p);
        }
      asm volatile("s_waitcnt lgkmcnt(0)" ::: "memory");
#pragma unroll
      for (int ms = 0; ms < 2; ++ms) {
        v8s af = *(const v8s*)&sPw[l15 * 72 + ms * 32 + quad * 8];
#pragma unroll
        for (int ct = 0; ct < 4; ++ct) {
          v8s bf = *(const v8s*)&sVc[(ct * 16 + l15) * 136 + (half * 2 + ms) * 32 + quad * 8];
          oacc[ct] = __builtin_amdgcn_mfma_f32_16x16x32_bf16(af, bf, oacc[ct], 0, 0, 0);
        }
      }
      asm volatile("s_waitcnt lgkmcnt(0)" ::: "memory");
    }
#pragma unroll
    for (int r = 0; r < 4; ++r) {
      float s = rsum[r];
      s += __shfl_xor(s, 8, 64);
      s += __shfl_xor(s, 4, 64);
      s += __shfl_xor(s, 2, 64);
      s += __shfl_xor(s, 1, 64);
      l_run[r] += s;
    }
    __syncthreads();
  }
  float inv[4];
#pragma unroll
  for (int r = 0; r < 4; ++r) inv[r] = __builtin_amdgcn_rcpf(l_run[r]);
  float* sOt = (float*)smem;
#pragma unroll
  for (int ct = 0; ct < 4; ++ct)
#pragma unroll
    for (int r = 0; r < 4; ++r)
      sOt[(ct * 16 + l15) * 132 + wave * 16 + quad * 4 + r] = oacc[ct][r] * inv[r];
  __syncthreads();
#pragma unroll
  for (int j = 0; j < 4; ++j) {
    int idx = tid + j * 512;
    int nv = idx & 31, c = idx >> 5;
    float4 o = *(const float4*)&sOt[c * 132 + nv * 4];
    size_t gaddr = (size_t)b * (64 * 4096) + (size_t)c * 4096 + (size_t)(qt * 128 + nv * 4);
    float4 xv = *(const float4*)(x + gaddr);
    float4 res = make_float4(xv.x + o.x, xv.y + o.y, xv.z + o.z, xv.w + o.w);
    *(float4*)(out + gaddr) = res;
  }
}

extern "C" void kernel_launch(void* const* d_in, const int* in_sizes, int n_in,
                              void* d_out, int out_size, void* d_ws, size_t ws_size,
                              hipStream_t stream) {
  const float* xin = (const float*)d_in[0];
  float* out = (float*)d_out;
  if (ws_size >= (size_t)WS_NEED) {
    unsigned short* fbf_t = (unsigned short*)((char*)d_ws + WS_FBF_T);
    unsigned short* fvp = (unsigned short*)((char*)d_ws + WS_FVP);
    float* g = (float*)((char*)d_ws + WS_G);
    float* bmax = (float*)((char*)d_ws + WS_BMAX);
    prep_kernel<<<dim3(512), dim3(256), 0, stream>>>(xin, fbf_t, fvp, g, bmax);
    chanattn_main<<<dim3(256), dim3(512), 0, stream>>>(xin, fbf_t, fvp, g, bmax, out);
  } else {
    chanattn_fallback<<<dim3(256), dim3(512), 0, stream>>>(xin, out);
  }
}